// Round 11
// baseline (887.623 us; speedup 1.0000x reference)
//
#include <hip/hip_runtime.h>

#define N_PRE 1024
#define N_POST 2048
#define SEQ_LEN 4096

// AMD BLIS/AOCL sgemm K-blocking: KC=512, naive splits -> K=1024 = [512,512].
// Per C element: C = rn(S1 + S2), each S_i a single-accumulator ascending-k
// fp32 chain. stim in {0,1} -> products exact -> FMA==mul+add, only the add
// grouping matters. (Eigen/XLA kc=512 yields the same grouping.)
#define KSPLIT 512

// Blocks FMA contraction (np's scan computes v*0.9 and +c as two separately
// rounded fp32 ufunc ops).
__device__ __forceinline__ float opaque(float x) {
  asm volatile("" : "+v"(x));
  return x;
}

__device__ __forceinline__ float load_dyn(const void* p, size_t idx, bool isbf) {
  if (isbf) {
    const unsigned short b = ((const unsigned short*)p)[idx];
    return __uint_as_float(((unsigned int)b) << 16);
  }
  return ((const float*)p)[idx];
}

// Input-dtype sniff (deterministic; established: weights fp32, stim bf16).
__device__ __forceinline__ int sniff_flags(const void* W, const void* S, int tid,
                                           int* flags_sh) {
  if (tid < 64) {
    const unsigned short* uw = (const unsigned short*)W;
    const float f = fabsf(__uint_as_float(((unsigned int)uw[tid * 2]) << 16));
    const bool big = !(f < 64.f);
    const unsigned long long wb = __ballot(big);
    const unsigned short* us = (const unsigned short*)S;
    int hit = 0;
    for (int j = 0; j < 64; ++j) hit |= (us[tid * 128 + 2 * j] == 0x3F80u) ? 1 : 0;
    const unsigned long long sb = __ballot(hit != 0);
    if (tid == 0) *flags_sh = ((wb == 0ull) ? 1 : 0) | ((sb != 0ull) ? 2 : 0);
  }
  __syncthreads();
  return *flags_sh;
}

// ---------------- GEMM: currents = weights @ stim, [512|512] chain ----------
__global__ __launch_bounds__(256) void snn_gemm_blis(const void* __restrict__ W,
                                                     const void* __restrict__ S,
                                                     float* __restrict__ C,
                                                     int t0, int chunkT) {
  __shared__ float As[16][68];  // [k][m]
  __shared__ float Bs[16][68];  // [k][t]
  __shared__ int flags_sh;
  const int tid = threadIdx.x;
  const int fl = sniff_flags(W, S, tid, &flags_sh);
  const bool w_bf = (fl & 1) != 0;
  const bool s_bf = (fl & 2) != 0;

  const int tx = tid & 15;   // t direction
  const int ty = tid >> 4;   // m direction
  const int m0 = blockIdx.y * 64;
  const int nl0 = blockIdx.x * 64;

  float acc0[4][4] = {{0.f}};
  float acc1[4][4] = {{0.f}};

  int k0 = 0;
#define GEMM_SEGMENT(ACC, KEND)                                                  \
  for (; k0 < (KEND); k0 += 16) {                                                \
    {                                                                            \
      const int r = tid >> 4, c = tid & 15;                                      \
      _Pragma("unroll") for (int j = 0; j < 4; ++j) {                            \
        const int rr = r + 16 * j;                                               \
        As[c][rr] = load_dyn(W, (size_t)(m0 + rr) * N_PRE + k0 + c, w_bf);       \
      }                                                                          \
    }                                                                            \
    {                                                                            \
      const int r = tid >> 6, c = tid & 63;                                      \
      _Pragma("unroll") for (int j = 0; j < 4; ++j) {                            \
        const int rr = r + 4 * j;                                                \
        Bs[rr][c] = load_dyn(S, (size_t)(k0 + rr) * SEQ_LEN + t0 + nl0 + c, s_bf); \
      }                                                                          \
    }                                                                            \
    __syncthreads();                                                             \
    _Pragma("unroll") for (int k = 0; k < 16; ++k) {                             \
      float a[4], b[4];                                                          \
      _Pragma("unroll") for (int i = 0; i < 4; ++i) a[i] = As[k][ty * 4 + i];    \
      _Pragma("unroll") for (int i = 0; i < 4; ++i) b[i] = Bs[k][tx * 4 + i];    \
      _Pragma("unroll") for (int i = 0; i < 4; ++i)                              \
          _Pragma("unroll") for (int j = 0; j < 4; ++j)                          \
              ACC[i][j] += a[i] * b[j]; /* product exact */                      \
    }                                                                            \
    __syncthreads();                                                             \
  }

  GEMM_SEGMENT(acc0, KSPLIT)
  GEMM_SEGMENT(acc1, N_PRE)
#undef GEMM_SEGMENT

#pragma unroll
  for (int i = 0; i < 4; ++i) {
    float r[4];
#pragma unroll
    for (int j = 0; j < 4; ++j) r[j] = acc0[i][j] + acc1[i][j];  // rn(S1+S2)
    float4 v4 = make_float4(r[0], r[1], r[2], r[3]);
    *(float4*)&C[(size_t)(m0 + ty * 4 + i) * chunkT + nl0 + tx * 4] = v4;
  }
}

// ---------------- exact LIF scan, strict fp32 ----------
#define ROWS 64
#define TT 32
__global__ __launch_bounds__(256) void snn_scan_f32(const float* __restrict__ cur,
                                                    float* __restrict__ spk,
                                                    float* __restrict__ vout,
                                                    float* __restrict__ v_carry,
                                                    int t0, int chunkT, int first) {
  __shared__ float c_tile[ROWS][TT + 1];
  __shared__ float s_tile[ROWS][TT + 1];
  __shared__ float v_tile[ROWS][TT + 1];
  const int tid = threadIdx.x;
  const int n0 = blockIdx.x * ROWS;

  float v = 0.0f;
  if (tid < ROWS && !first) v = v_carry[n0 + tid];

  for (int tt = 0; tt < chunkT; tt += TT) {
#pragma unroll
    for (int j = 0; j < (ROWS * TT) / 256; ++j) {
      const int idx = tid + 256 * j;
      const int row = idx / TT;
      const int cc = idx % TT;
      c_tile[row][cc] = cur[(size_t)(n0 + row) * chunkT + tt + cc];
    }
    __syncthreads();
    if (tid < ROWS) {
#pragma unroll
      for (int k = 0; k < TT; ++k) {
        const float leak = opaque(v * 0.9f);  // rn(v*0.9f)
        v = leak + c_tile[tid][k];            // rn(+c)
        const bool fired = (v >= 1.0f);
        s_tile[tid][k] = fired ? 1.0f : 0.0f;
        v = fired ? 0.0f : v;
        v_tile[tid][k] = v;
      }
    }
    __syncthreads();
#pragma unroll
    for (int j = 0; j < (ROWS * TT) / 256; ++j) {
      const int idx = tid + 256 * j;
      const int row = idx / TT;
      const int cc = idx % TT;
      const size_t g = (size_t)(n0 + row) * SEQ_LEN + t0 + tt + cc;
      spk[g] = s_tile[row][cc];
      vout[g] = v_tile[row][cc];
    }
    __syncthreads();
  }

  if (tid < ROWS) v_carry[n0 + tid] = v;
}

// ---------------- fused fallback (ws too small), same [512|512] chain -------
__global__ __launch_bounds__(256) void snn_fused_blis(const void* __restrict__ W,
                                                      const void* __restrict__ S,
                                                      float* __restrict__ spk,
                                                      float* __restrict__ vout) {
  __shared__ float As[16][68];
  __shared__ float Bs[16][68];
  __shared__ float Ct[64][65];
  __shared__ float vsh[64];
  __shared__ int flags_sh;
  const int tid = threadIdx.x;
  const int fl = sniff_flags(W, S, tid, &flags_sh);
  const bool w_bf = (fl & 1) != 0;
  const bool s_bf = (fl & 2) != 0;

  const int tx = tid & 15;
  const int ty = tid >> 4;
  const int m0 = blockIdx.x * 64;
  if (tid < 64) vsh[tid] = 0.0f;

  for (int t0 = 0; t0 < SEQ_LEN; t0 += 64) {
    float acc0[4][4] = {{0.f}};
    float acc1[4][4] = {{0.f}};
    int k0 = 0;
#define FUSED_SEGMENT(ACC, KEND)                                                 \
    for (; k0 < (KEND); k0 += 16) {                                              \
      {                                                                          \
        const int r = tid >> 4, c = tid & 15;                                    \
        _Pragma("unroll") for (int j = 0; j < 4; ++j)                            \
            As[c][r + 16 * j] =                                                  \
                load_dyn(W, (size_t)(m0 + r + 16 * j) * N_PRE + k0 + c, w_bf);   \
      }                                                                          \
      {                                                                          \
        const int r = tid >> 6, c = tid & 63;                                    \
        _Pragma("unroll") for (int j = 0; j < 4; ++j)                            \
            Bs[r + 4 * j][c] =                                                   \
                load_dyn(S, (size_t)(k0 + r + 4 * j) * SEQ_LEN + t0 + c, s_bf);  \
      }                                                                          \
      __syncthreads();                                                           \
      _Pragma("unroll") for (int k = 0; k < 16; ++k) {                           \
        _Pragma("unroll") for (int i = 0; i < 4; ++i)                            \
            _Pragma("unroll") for (int j = 0; j < 4; ++j)                        \
                ACC[i][j] += As[k][ty * 4 + i] * Bs[k][tx * 4 + j];              \
      }                                                                          \
      __syncthreads();                                                           \
    }

    FUSED_SEGMENT(acc0, KSPLIT)
    FUSED_SEGMENT(acc1, N_PRE)
#undef FUSED_SEGMENT

#pragma unroll
    for (int i = 0; i < 4; ++i)
#pragma unroll
      for (int j = 0; j < 4; ++j) Ct[ty * 4 + i][tx * 4 + j] = acc0[i][j] + acc1[i][j];
    __syncthreads();
    if (tid < 64) {
      float v = vsh[tid];
#pragma unroll
      for (int k = 0; k < 64; ++k) {
        const float leak = opaque(v * 0.9f);
        v = leak + Ct[tid][k];
        const bool fired = (v >= 1.0f);
        const size_t g = (size_t)(m0 + tid) * SEQ_LEN + t0 + k;
        spk[g] = fired ? 1.0f : 0.0f;
        v = fired ? 0.0f : v;
        vout[g] = v;
      }
      vsh[tid] = v;
    }
    __syncthreads();
  }
}

extern "C" void kernel_launch(void* const* d_in, const int* in_sizes, int n_in,
                              void* d_out, int out_size, void* d_ws, size_t ws_size,
                              hipStream_t stream) {
  const void* stim = d_in[0];
  const void* weights = d_in[1];
  if (n_in >= 2 && in_sizes[0] == N_POST * N_PRE && in_sizes[1] == N_PRE * SEQ_LEN) {
    weights = d_in[0];
    stim = d_in[1];
  }

  float* spk = (float*)d_out;                     // output 0: spikes [N_POST, SEQ_LEN] fp32
  float* vout = spk + (size_t)N_POST * SEQ_LEN;   // output 1: v      [N_POST, SEQ_LEN] fp32

  const size_t carry_bytes = (size_t)N_POST * sizeof(float);
  float* v_carry = nullptr;
  size_t avail = 0;
  if (ws_size > carry_bytes + 8) {
    const size_t coff = (ws_size - carry_bytes) & ~(size_t)15;
    v_carry = (float*)((char*)d_ws + coff);
    avail = coff;
  }
  int chunkT = (int)((avail / ((size_t)N_POST * sizeof(float))) / 64 * 64);
  if (chunkT > SEQ_LEN) chunkT = SEQ_LEN;

  if (chunkT >= 64) {
    float* cur = (float*)d_ws;
    for (int t0 = 0; t0 < SEQ_LEN; t0 += chunkT) {
      const int ct = (SEQ_LEN - t0 < chunkT) ? (SEQ_LEN - t0) : chunkT;
      snn_gemm_blis<<<dim3(ct / 64, N_POST / 64), dim3(256), 0, stream>>>(weights, stim, cur, t0, ct);
      snn_scan_f32<<<dim3(N_POST / ROWS), dim3(256), 0, stream>>>(cur, spk, vout, v_carry, t0, ct,
                                                                  t0 == 0);
    }
  } else {
    snn_fused_blis<<<dim3(N_POST / 64), dim3(256), 0, stream>>>(weights, stim, spk, vout);
  }
}

// Round 12
// 410.929 us; speedup vs baseline: 2.1600x; 2.1600x over previous
//
#include <hip/hip_runtime.h>

#define N_PRE 1024
#define N_POST 2048
#define SEQ_LEN 4096

// Reference-verified numerics (R11 PASS): per C element two fp32 segment
// chains k in [0,512) and [512,1024), ascending, single accumulator each,
// combined rn(S1+S2). stim in {0,1} -> products exact -> FMA == mul+add.
// Scan: v = rn(rn(v*0.9f) + c), fire >= 1.0f, reset 0. DO NOT REORDER.
#define KSPLIT 512

__device__ __forceinline__ float opaque(float x) {
  asm volatile("" : "+v"(x));
  return x;
}

__device__ __forceinline__ float load_dyn(const void* p, size_t idx, bool isbf) {
  if (isbf) {
    const unsigned short b = ((const unsigned short*)p)[idx];
    return __uint_as_float(((unsigned int)b) << 16);
  }
  return ((const float*)p)[idx];
}

// Input-dtype sniff (established: weights fp32, stim bf16; kept for safety).
__device__ __forceinline__ int sniff_flags(const void* W, const void* S, int tid,
                                           int* flags_sh) {
  if (tid < 64) {
    const unsigned short* uw = (const unsigned short*)W;
    const float f = fabsf(__uint_as_float(((unsigned int)uw[tid * 2]) << 16));
    const bool big = !(f < 64.f);
    const unsigned long long wb = __ballot(big);
    const unsigned short* us = (const unsigned short*)S;
    int hit = 0;
    for (int j = 0; j < 64; ++j) hit |= (us[tid * 128 + 2 * j] == 0x3F80u) ? 1 : 0;
    const unsigned long long sb = __ballot(hit != 0);
    if (tid == 0) *flags_sh = ((wb == 0ull) ? 1 : 0) | ((sb != 0ull) ? 2 : 0);
  }
  __syncthreads();
  return *flags_sh;
}

// ---------------- GEMM v2: 128x128 tile, 8x8 microtile, [512|512] chain -----
// LDS row stride 132: 16B-aligned rows (528B) + bank-spread (132%32=4).
__global__ __launch_bounds__(256, 2) void snn_gemm_v2(const void* __restrict__ W,
                                                      const void* __restrict__ S,
                                                      float* __restrict__ C,
                                                      int t0, int chunkT) {
  __shared__ float As[16][132];  // [k][m]
  __shared__ float Bs[16][132];  // [k][t]
  __shared__ int flags_sh;
  const int tid = threadIdx.x;
  const int fl = sniff_flags(W, S, tid, &flags_sh);
  const bool w_bf = (fl & 1) != 0;
  const bool s_bf = (fl & 2) != 0;

  const int tx = tid & 15;   // t dim, 8 cols each
  const int ty = tid >> 4;   // m dim, 8 rows each
  const int m0 = blockIdx.y * 128;
  const int nl0 = blockIdx.x * 128;

  float acc0[8][8] = {{0.f}};
  float acc1[8][8] = {{0.f}};

  int k0 = 0;
#define KTILE_BODY(ACC)                                                          \
  {                                                                              \
    /* ---- stage A: W[m0..+128][k0..+16] -> As[k][m] ---- */                    \
    if (!w_bf) {                                                                 \
      const float* Wf = (const float*)W;                                         \
      const int row = tid >> 2;                                                  \
      const int c4 = (tid & 3) * 4;                                              \
      _Pragma("unroll") for (int h = 0; h < 2; ++h) {                            \
        const int m = row + 64 * h;                                              \
        const float4 va =                                                        \
            *(const float4*)&Wf[(size_t)(m0 + m) * N_PRE + k0 + c4];             \
        As[c4 + 0][m] = va.x; As[c4 + 1][m] = va.y;                              \
        As[c4 + 2][m] = va.z; As[c4 + 3][m] = va.w;                              \
      }                                                                          \
    } else {                                                                     \
      _Pragma("unroll") for (int e = 0; e < 8; ++e) {                            \
        const int idx = tid * 8 + e;                                             \
        const int m = idx >> 4, c = idx & 15;                                    \
        As[c][m] = load_dyn(W, (size_t)(m0 + m) * N_PRE + k0 + c, true);         \
      }                                                                          \
    }                                                                            \
    /* ---- stage B: S[k0..+16][t0+nl0..+128] -> Bs[k][t] ---- */                \
    {                                                                            \
      const int r = tid >> 4;                                                    \
      const int c8 = (tid & 15) * 8;                                             \
      if (s_bf) {                                                                \
        const unsigned short* Sb = (const unsigned short*)S;                     \
        const uint4 u =                                                          \
            *(const uint4*)&Sb[(size_t)(k0 + r) * SEQ_LEN + t0 + nl0 + c8];      \
        Bs[r][c8 + 0] = __uint_as_float(u.x << 16);                              \
        Bs[r][c8 + 1] = __uint_as_float(u.x & 0xFFFF0000u);                      \
        Bs[r][c8 + 2] = __uint_as_float(u.y << 16);                              \
        Bs[r][c8 + 3] = __uint_as_float(u.y & 0xFFFF0000u);                      \
        Bs[r][c8 + 4] = __uint_as_float(u.z << 16);                              \
        Bs[r][c8 + 5] = __uint_as_float(u.z & 0xFFFF0000u);                      \
        Bs[r][c8 + 6] = __uint_as_float(u.w << 16);                              \
        Bs[r][c8 + 7] = __uint_as_float(u.w & 0xFFFF0000u);                      \
      } else {                                                                   \
        const float* Sf = (const float*)S;                                       \
        const size_t base = (size_t)(k0 + r) * SEQ_LEN + t0 + nl0 + c8;          \
        *(float4*)&Bs[r][c8] = *(const float4*)&Sf[base];                        \
        *(float4*)&Bs[r][c8 + 4] = *(const float4*)&Sf[base + 4];                \
      }                                                                          \
    }                                                                            \
    __syncthreads();                                                             \
    _Pragma("unroll") for (int k = 0; k < 16; ++k) {                             \
      float a[8], b[8];                                                          \
      *(float4*)&a[0] = *(const float4*)&As[k][ty * 8];                          \
      *(float4*)&a[4] = *(const float4*)&As[k][ty * 8 + 4];                      \
      *(float4*)&b[0] = *(const float4*)&Bs[k][tx * 8];                          \
      *(float4*)&b[4] = *(const float4*)&Bs[k][tx * 8 + 4];                      \
      _Pragma("unroll") for (int i = 0; i < 8; ++i)                              \
          _Pragma("unroll") for (int j = 0; j < 8; ++j)                          \
              ACC[i][j] += a[i] * b[j]; /* exact product: add-chain only */      \
    }                                                                            \
    __syncthreads();                                                             \
  }

  for (; k0 < KSPLIT; k0 += 16) KTILE_BODY(acc0)
  for (; k0 < N_PRE; k0 += 16) KTILE_BODY(acc1)
#undef KTILE_BODY

#pragma unroll
  for (int i = 0; i < 8; ++i) {
    float r[8];
#pragma unroll
    for (int j = 0; j < 8; ++j) r[j] = acc0[i][j] + acc1[i][j];  // rn(S1+S2)
    float* dst = &C[(size_t)(m0 + ty * 8 + i) * chunkT + nl0 + tx * 8];
    *(float4*)&dst[0] = make_float4(r[0], r[1], r[2], r[3]);
    *(float4*)&dst[4] = make_float4(r[4], r[5], r[6], r[7]);
  }
}

// ---------------- Scan v2: 16 neurons/block (128 blocks), dbuf LDS ----------
#define SROWS 16
#define STT 64
#define SPAD 68  // row stride: 272B (16B-aligned), 68%32=4 bank spread
__global__ __launch_bounds__(256) void snn_scan_v2(const float* __restrict__ cur,
                                                   float* __restrict__ spk,
                                                   float* __restrict__ vout,
                                                   float* __restrict__ v_carry,
                                                   int t0, int chunkT, int first) {
  __shared__ float c_t[2][SROWS][SPAD];
  __shared__ float s_t[SROWS][SPAD];
  __shared__ float v_t[SROWS][SPAD];
  const int tid = threadIdx.x;
  const int n0 = blockIdx.x * SROWS;
  const int row = tid >> 4;        // 0..15
  const int c4 = (tid & 15) * 4;   // 0..60

  float v = 0.0f;
  if (tid < SROWS && !first) v = v_carry[n0 + tid];

  const int ntiles = chunkT / STT;
  // prologue: load tile 0
  *(float4*)&c_t[0][row][c4] =
      *(const float4*)&cur[(size_t)(n0 + row) * chunkT + 0 + c4];
  __syncthreads();

  for (int it = 0; it < ntiles; ++it) {
    const int buf = it & 1;
    // prefetch next tile into the other buffer (independent of scan)
    if (it + 1 < ntiles) {
      *(float4*)&c_t[buf ^ 1][row][c4] =
          *(const float4*)&cur[(size_t)(n0 + row) * chunkT + (it + 1) * STT + c4];
    }
    if (tid < SROWS) {
#pragma unroll
      for (int g = 0; g < STT / 16; ++g) {
        float c[16], s[16], vv[16];
        *(float4*)&c[0] = *(const float4*)&c_t[buf][tid][g * 16];
        *(float4*)&c[4] = *(const float4*)&c_t[buf][tid][g * 16 + 4];
        *(float4*)&c[8] = *(const float4*)&c_t[buf][tid][g * 16 + 8];
        *(float4*)&c[12] = *(const float4*)&c_t[buf][tid][g * 16 + 12];
#pragma unroll
        for (int k = 0; k < 16; ++k) {
          const float leak = opaque(v * 0.9f);  // rn(v*0.9f)
          v = leak + c[k];                      // rn(+c)
          const bool fired = (v >= 1.0f);
          s[k] = fired ? 1.0f : 0.0f;
          v = fired ? 0.0f : v;
          vv[k] = v;
        }
        *(float4*)&s_t[tid][g * 16] = make_float4(s[0], s[1], s[2], s[3]);
        *(float4*)&s_t[tid][g * 16 + 4] = make_float4(s[4], s[5], s[6], s[7]);
        *(float4*)&s_t[tid][g * 16 + 8] = make_float4(s[8], s[9], s[10], s[11]);
        *(float4*)&s_t[tid][g * 16 + 12] = make_float4(s[12], s[13], s[14], s[15]);
        *(float4*)&v_t[tid][g * 16] = make_float4(vv[0], vv[1], vv[2], vv[3]);
        *(float4*)&v_t[tid][g * 16 + 4] = make_float4(vv[4], vv[5], vv[6], vv[7]);
        *(float4*)&v_t[tid][g * 16 + 8] = make_float4(vv[8], vv[9], vv[10], vv[11]);
        *(float4*)&v_t[tid][g * 16 + 12] = make_float4(vv[12], vv[13], vv[14], vv[15]);
      }
    }
    __syncthreads();  // scan done (s_t/v_t valid) + prefetch write landed
    {
      const size_t g = (size_t)(n0 + row) * SEQ_LEN + t0 + it * STT + c4;
      *(float4*)&spk[g] = *(const float4*)&s_t[row][c4];
      *(float4*)&vout[g] = *(const float4*)&v_t[row][c4];
    }
    __syncthreads();  // stores read s_t/v_t before next-tile scan overwrites
  }

  if (tid < SROWS) v_carry[n0 + tid] = v;
}

// ---------------- fused fallback (ws too small), same [512|512] chain -------
__global__ __launch_bounds__(256) void snn_fused_blis(const void* __restrict__ W,
                                                      const void* __restrict__ S,
                                                      float* __restrict__ spk,
                                                      float* __restrict__ vout) {
  __shared__ float As[16][68];
  __shared__ float Bs[16][68];
  __shared__ float Ct[64][65];
  __shared__ float vsh[64];
  __shared__ int flags_sh;
  const int tid = threadIdx.x;
  const int fl = sniff_flags(W, S, tid, &flags_sh);
  const bool w_bf = (fl & 1) != 0;
  const bool s_bf = (fl & 2) != 0;

  const int tx = tid & 15;
  const int ty = tid >> 4;
  const int m0 = blockIdx.x * 64;
  if (tid < 64) vsh[tid] = 0.0f;

  for (int t0 = 0; t0 < SEQ_LEN; t0 += 64) {
    float acc0[4][4] = {{0.f}};
    float acc1[4][4] = {{0.f}};
    int k0 = 0;
#define FUSED_SEGMENT(ACC, KEND)                                                 \
    for (; k0 < (KEND); k0 += 16) {                                              \
      {                                                                          \
        const int r = tid >> 4, c = tid & 15;                                    \
        _Pragma("unroll") for (int j = 0; j < 4; ++j)                            \
            As[c][r + 16 * j] =                                                  \
                load_dyn(W, (size_t)(m0 + r + 16 * j) * N_PRE + k0 + c, w_bf);   \
      }                                                                          \
      {                                                                          \
        const int r = tid >> 6, c = tid & 63;                                    \
        _Pragma("unroll") for (int j = 0; j < 4; ++j)                            \
            Bs[r + 4 * j][c] =                                                   \
                load_dyn(S, (size_t)(k0 + r + 4 * j) * SEQ_LEN + t0 + c, s_bf);  \
      }                                                                          \
      __syncthreads();                                                           \
      _Pragma("unroll") for (int k = 0; k < 16; ++k) {                           \
        _Pragma("unroll") for (int i = 0; i < 4; ++i)                            \
            _Pragma("unroll") for (int j = 0; j < 4; ++j)                        \
                ACC[i][j] += As[k][ty * 4 + i] * Bs[k][tx * 4 + j];              \
      }                                                                          \
      __syncthreads();                                                           \
    }

    FUSED_SEGMENT(acc0, KSPLIT)
    FUSED_SEGMENT(acc1, N_PRE)
#undef FUSED_SEGMENT

#pragma unroll
    for (int i = 0; i < 4; ++i)
#pragma unroll
      for (int j = 0; j < 4; ++j) Ct[ty * 4 + i][tx * 4 + j] = acc0[i][j] + acc1[i][j];
    __syncthreads();
    if (tid < 64) {
      float v = vsh[tid];
#pragma unroll
      for (int k = 0; k < 64; ++k) {
        const float leak = opaque(v * 0.9f);
        v = leak + Ct[tid][k];
        const bool fired = (v >= 1.0f);
        const size_t g = (size_t)(m0 + tid) * SEQ_LEN + t0 + k;
        spk[g] = fired ? 1.0f : 0.0f;
        v = fired ? 0.0f : v;
        vout[g] = v;
      }
      vsh[tid] = v;
    }
    __syncthreads();
  }
}

extern "C" void kernel_launch(void* const* d_in, const int* in_sizes, int n_in,
                              void* d_out, int out_size, void* d_ws, size_t ws_size,
                              hipStream_t stream) {
  const void* stim = d_in[0];
  const void* weights = d_in[1];
  if (n_in >= 2 && in_sizes[0] == N_POST * N_PRE && in_sizes[1] == N_PRE * SEQ_LEN) {
    weights = d_in[0];
    stim = d_in[1];
  }

  float* spk = (float*)d_out;                     // output 0: spikes [N_POST, SEQ_LEN] fp32
  float* vout = spk + (size_t)N_POST * SEQ_LEN;   // output 1: v      [N_POST, SEQ_LEN] fp32

  const size_t carry_bytes = (size_t)N_POST * sizeof(float);
  float* v_carry = nullptr;
  size_t avail = 0;
  if (ws_size > carry_bytes + 8) {
    const size_t coff = (ws_size - carry_bytes) & ~(size_t)15;
    v_carry = (float*)((char*)d_ws + coff);
    avail = coff;
  }
  int chunkT = (int)((avail / ((size_t)N_POST * sizeof(float))) / 128 * 128);
  if (chunkT > SEQ_LEN) chunkT = SEQ_LEN;

  if (chunkT >= 128) {
    float* cur = (float*)d_ws;
    for (int t0 = 0; t0 < SEQ_LEN; t0 += chunkT) {
      const int ct = (SEQ_LEN - t0 < chunkT) ? (SEQ_LEN - t0) : chunkT;  // mult of 128
      snn_gemm_v2<<<dim3(ct / 128, N_POST / 128), dim3(256), 0, stream>>>(weights, stim, cur,
                                                                          t0, ct);
      snn_scan_v2<<<dim3(N_POST / SROWS), dim3(256), 0, stream>>>(cur, spk, vout, v_carry,
                                                                  t0, ct, t0 == 0);
    }
  } else {
    snn_fused_blis<<<dim3(N_POST / 64), dim3(256), 0, stream>>>(weights, stim, spk, vout);
  }
}